// Round 1
// baseline (163.099 us; speedup 1.0000x reference)
//
#include <hip/hip_runtime.h>

#define NPAIR 10
#define NTRI  10

__device__ __constant__ const int c_i1[NTRI]  = {0,0,1,0,1,2,4,4,5,7};
__device__ __constant__ const int c_i2[NTRI]  = {4,5,7,6,8,9,7,8,9,9};
__device__ __constant__ const int c_i12[NTRI] = {1,2,2,3,3,3,5,6,6,8};

__global__ __launch_bounds__(256) void accum_loss_kernel(
    const float* __restrict__ rotas,   // [NPAIR][B][3][3]
    const float* __restrict__ transs,  // [NPAIR][B][3]
    float* __restrict__ block_sums,    // [gridDim.x]
    int B)
{
    const int b = blockIdx.x * blockDim.x + threadIdx.x;

    float loss = 0.0f;
    if (b < B) {
        float R[NPAIR][9];
        float t[NPAIR][3];
#pragma unroll
        for (int p = 0; p < NPAIR; ++p) {
            const float* rp = rotas + ((size_t)p * B + b) * 9;
#pragma unroll
            for (int k = 0; k < 9; ++k) R[p][k] = rp[k];
            const float* tp = transs + ((size_t)p * B + b) * 3;
#pragma unroll
            for (int k = 0; k < 3; ++k) t[p][k] = tp[k];
        }

        float rl = 0.0f, tl = 0.0f;
#pragma unroll
        for (int tr = 0; tr < NTRI; ++tr) {
            const float* R1  = R[c_i1[tr]];
            const float* R2  = R[c_i2[tr]];
            const float* R12 = R[c_i12[tr]];
            const float* t1  = t[c_i1[tr]];
            const float* t2  = t[c_i2[tr]];
            const float* t12 = t[c_i12[tr]];
#pragma unroll
            for (int i = 0; i < 3; ++i) {
#pragma unroll
                for (int j = 0; j < 3; ++j) {
                    float f = fmaf(R1[i*3+0], R2[0*3+j],
                              fmaf(R1[i*3+1], R2[1*3+j],
                                   R1[i*3+2] * R2[2*3+j]));
                    float d = f - R12[i*3+j];
                    rl = fmaf(d, d, rl);
                }
                float ft = fmaf(R1[i*3+0], t1[0],
                           fmaf(R1[i*3+1], t1[1],
                                R1[i*3+2] * t1[2])) + t2[i];
                float dt = ft - t12[i];
                tl = fmaf(dt, dt, tl);
            }
        }
        loss = fmaf(rl, 50.0f, tl);
    }

    // wave (64-lane) reduction
#pragma unroll
    for (int off = 32; off >= 1; off >>= 1)
        loss += __shfl_down(loss, off, 64);

    __shared__ float ws[4];
    const int lane = threadIdx.x & 63;
    const int wid  = threadIdx.x >> 6;
    if (lane == 0) ws[wid] = loss;
    __syncthreads();
    if (threadIdx.x == 0)
        block_sums[blockIdx.x] = ws[0] + ws[1] + ws[2] + ws[3];
}

__global__ __launch_bounds__(256) void final_reduce_kernel(
    const float* __restrict__ block_sums, float* __restrict__ out, int n)
{
    float s = 0.0f;
    for (int i = threadIdx.x; i < n; i += blockDim.x) s += block_sums[i];
#pragma unroll
    for (int off = 32; off >= 1; off >>= 1)
        s += __shfl_down(s, off, 64);

    __shared__ float ws[4];
    const int lane = threadIdx.x & 63;
    const int wid  = threadIdx.x >> 6;
    if (lane == 0) ws[wid] = s;
    __syncthreads();
    if (threadIdx.x == 0)
        out[0] = ws[0] + ws[1] + ws[2] + ws[3];
}

extern "C" void kernel_launch(void* const* d_in, const int* in_sizes, int n_in,
                              void* d_out, int out_size, void* d_ws, size_t ws_size,
                              hipStream_t stream)
{
    const float* rotas  = (const float*)d_in[0];
    const float* transs = (const float*)d_in[1];
    float* out = (float*)d_out;

    const int B = in_sizes[0] / (NPAIR * 9);   // 262144
    const int threads = 256;
    const int blocks  = (B + threads - 1) / threads;  // 1024

    float* block_sums = (float*)d_ws;  // blocks * 4 bytes

    accum_loss_kernel<<<blocks, threads, 0, stream>>>(rotas, transs, block_sums, B);
    final_reduce_kernel<<<1, threads, 0, stream>>>(block_sums, out, blocks);
}

// Round 3
// 162.809 us; speedup vs baseline: 1.0018x; 1.0018x over previous
//
#include <hip/hip_runtime.h>

#define NPAIR 10
#define NTRI  10

constexpr int c_i1[NTRI]  = {0,0,1,0,1,2,4,4,5,7};
constexpr int c_i2[NTRI]  = {4,5,7,6,8,9,7,8,9,9};
constexpr int c_i12[NTRI] = {1,2,2,3,3,3,5,6,6,8};

// lgkmcnt(0) only; vmcnt/expcnt left at max so global prefetch stays in flight.
#define LDS_FENCE() do {                      \
    __builtin_amdgcn_s_waitcnt(0xC07F);       \
    __builtin_amdgcn_wave_barrier();          \
} while (0)

__global__ __launch_bounds__(256) void accum_loss_kernel(
    const float* __restrict__ rotas,   // [NPAIR][B][3][3]
    const float* __restrict__ transs,  // [NPAIR][B][3]
    float* __restrict__ block_sums,    // [gridDim.x]
    int B)
{
    const int tid  = threadIdx.x;
    const int lane = tid & 63;
    const int wave = tid >> 6;

    // Per-wave private staging; cross-lane exchange is wave-internal only, so
    // wave-level ordering (LDS_FENCE) suffices — no __syncthreads (its
    // vmcnt(0) drain would serialize the global prefetch each iteration).
    __shared__ float sR[2][4][576];   // 64 records x 9 floats per wave
    __shared__ float sT[2][4][192];   // 64 records x 3 floats per wave

    const int wb0 = blockIdx.x * 256 + wave * 64;  // first record of this wave

    float R[NPAIR][9];
    float t[NPAIR][3];
    float gR[9], gT[3];  // staging registers (coalesced order)

    {
        const float* rsrc = rotas  + ((size_t)0 * B + wb0) * 9;
        const float* tsrc = transs + ((size_t)0 * B + wb0) * 3;
#pragma unroll
        for (int k = 0; k < 9; ++k) gR[k] = rsrc[k * 64 + lane];
#pragma unroll
        for (int k = 0; k < 3; ++k) gT[k] = tsrc[k * 64 + lane];
    }

#pragma unroll
    for (int p = 0; p < NPAIR; ++p) {
        const int buf = p & 1;
        // record-major order preserved: sR[d] = chunk[d]
#pragma unroll
        for (int k = 0; k < 9; ++k) sR[buf][wave][k * 64 + lane] = gR[k];
#pragma unroll
        for (int k = 0; k < 3; ++k) sT[buf][wave][k * 64 + lane] = gT[k];

        // order: this wave's LDS writes land before the transpose reads
        LDS_FENCE();

        // prefetch next pair (global, stays in flight across the exchange)
        if (p + 1 < NPAIR) {
            const float* rsrc = rotas  + ((size_t)(p + 1) * B + wb0) * 9;
            const float* tsrc = transs + ((size_t)(p + 1) * B + wb0) * 3;
#pragma unroll
            for (int k = 0; k < 9; ++k) gR[k] = rsrc[k * 64 + lane];
#pragma unroll
            for (int k = 0; k < 3; ++k) gT[k] = tsrc[k * 64 + lane];
        }

        // transpose read: record `lane`, stride 9/3 -> 2 lanes/bank (free)
#pragma unroll
        for (int k = 0; k < 9; ++k) R[p][k] = sR[buf][wave][lane * 9 + k];
#pragma unroll
        for (int k = 0; k < 3; ++k) t[p][k] = sT[buf][wave][lane * 3 + k];

        // order: reads of pair p complete before writes of pair p+2 (same buf)
        LDS_FENCE();
    }

    float rl = 0.0f, tl = 0.0f;
#pragma unroll
    for (int tr = 0; tr < NTRI; ++tr) {
        const float* R1  = R[c_i1[tr]];
        const float* R2  = R[c_i2[tr]];
        const float* R12 = R[c_i12[tr]];
        const float* t1  = t[c_i1[tr]];
        const float* t2  = t[c_i2[tr]];
        const float* t12 = t[c_i12[tr]];
#pragma unroll
        for (int i = 0; i < 3; ++i) {
#pragma unroll
            for (int j = 0; j < 3; ++j) {
                float f = fmaf(R1[i*3+0], R2[0*3+j],
                          fmaf(R1[i*3+1], R2[1*3+j],
                               R1[i*3+2] * R2[2*3+j]));
                float d = f - R12[i*3+j];
                rl = fmaf(d, d, rl);
            }
            float ft = fmaf(R1[i*3+0], t1[0],
                       fmaf(R1[i*3+1], t1[1],
                            R1[i*3+2] * t1[2])) + t2[i];
            float dt = ft - t12[i];
            tl = fmaf(dt, dt, tl);
        }
    }
    float loss = fmaf(rl, 50.0f, tl);

    // wave (64-lane) reduction
#pragma unroll
    for (int off = 32; off >= 1; off >>= 1)
        loss += __shfl_down(loss, off, 64);

    __shared__ float ws[4];
    if (lane == 0) ws[wave] = loss;
    __syncthreads();
    if (tid == 0)
        block_sums[blockIdx.x] = ws[0] + ws[1] + ws[2] + ws[3];
}

__global__ __launch_bounds__(256) void final_reduce_kernel(
    const float* __restrict__ block_sums, float* __restrict__ out, int n)
{
    float s = 0.0f;
    for (int i = threadIdx.x; i < n; i += blockDim.x) s += block_sums[i];
#pragma unroll
    for (int off = 32; off >= 1; off >>= 1)
        s += __shfl_down(s, off, 64);

    __shared__ float ws[4];
    const int lane = threadIdx.x & 63;
    const int wid  = threadIdx.x >> 6;
    if (lane == 0) ws[wid] = s;
    __syncthreads();
    if (threadIdx.x == 0)
        out[0] = ws[0] + ws[1] + ws[2] + ws[3];
}

extern "C" void kernel_launch(void* const* d_in, const int* in_sizes, int n_in,
                              void* d_out, int out_size, void* d_ws, size_t ws_size,
                              hipStream_t stream)
{
    const float* rotas  = (const float*)d_in[0];
    const float* transs = (const float*)d_in[1];
    float* out = (float*)d_out;

    const int B = in_sizes[0] / (NPAIR * 9);   // 262144
    const int threads = 256;
    const int blocks  = B / threads;           // 1024

    float* block_sums = (float*)d_ws;

    accum_loss_kernel<<<blocks, threads, 0, stream>>>(rotas, transs, block_sums, B);
    final_reduce_kernel<<<1, threads, 0, stream>>>(block_sums, out, blocks);
}